// Round 7
// baseline (356.427 us; speedup 1.0000x reference)
//
#include <hip/hip_runtime.h>

// pred, target: [32,1,1024,1024] f32 -> scalar f32 = mean((softplus(p)-p*t)*w),
// w = 0.1 on 5x5 morphological gradient of binarized target, gated on
// cond = (t.max()==1 && t.min()==0).
//
// R7: fill-shaped flat kernels. R6 post-mortem: pipeline+launch_bounds hurt
// (VGPR 28, occ 70%, 133us); harness fill hits 7 TB/s at 9.8% occupancy ->
// the limiter is band/barrier structure, not BW or occupancy. New chain:
//   bbl_bits: flat grid-stride target -> 4MB bit plane + min/max (no LDS).
//   bbl_edge: bit plane -> edge plane via shfl-based 5x5 morphology (no LDS).
//   bbl_loss: flat grid-stride pred + wave-uniform (scalar) bit-words, no
//             barriers until final reduce.
// Bit layout: word W = row*16 + it*4 + m holds col 256*it + 4*lane + m at
// bit `lane` (ballot-native, unchanged from R0).
// R0 fused kernel kept as fallback if ws_size < 8MB + 64B.

#define IMG     1024
#define BAND    32
#define NBANDS  (IMG / BAND)     // 32
#define NIMG    32
#define WORDS   16               // 1024 cols / 64 bits
#define HALO    2
#define MAXROWS (BAND + 2 * HALO)
#define NROWS   (NIMG * IMG)     // 32768
#define NGRP    (NROWS * 4)      // 131072 float4-groups of 256 cols
#define NWAVES  8192             // 2048 blocks x 4 waves
#define NTOT    33554432.0

typedef unsigned long long u64;

__device__ __forceinline__ unsigned encf(float f) {
    unsigned u = __float_as_uint(f);
    return (u & 0x80000000u) ? ~u : (u | 0x80000000u);
}
__device__ __forceinline__ float decf(unsigned e) {
    unsigned u = (e & 0x80000000u) ? (e & 0x7fffffffu) : ~e;
    return __uint_as_float(u);
}

__global__ void bbl_init(double* dws, unsigned* uws) {
    if (threadIdx.x == 0) {
        dws[0] = 0.0; dws[1] = 0.0;
        uws[0] = 0xFFFFFFFFu;   // running min (encoded)
        uws[1] = 0u;            // running max (encoded)
    }
}

// ---------------- K1: target -> bit plane + min/max (flat, no barriers) -----
__global__ __launch_bounds__(256) void bbl_bits(
        const float* __restrict__ target,
        u64* __restrict__ bits, unsigned* __restrict__ uws) {
    __shared__ unsigned redMn[4], redMx[4];
    const int tid  = threadIdx.x;
    const int lane = tid & 63;
    const int wv   = tid >> 6;
    const int waveId = __builtin_amdgcn_readfirstlane(blockIdx.x * 4 + wv);

    float vmin = 3.4e38f, vmax = -3.4e38f;
    const float4* tp = (const float4*)target;

    for (int g = waveId; g < NGRP; g += 2 * NWAVES) {   // 8 iterations
        const int g2 = g + NWAVES;
        float4 a = tp[(size_t)g  * 64 + lane];
        float4 b = tp[(size_t)g2 * 64 + lane];

        vmin = fminf(vmin, fminf(fminf(a.x, a.y), fminf(a.z, a.w)));
        vmax = fmaxf(vmax, fmaxf(fmaxf(a.x, a.y), fmaxf(a.z, a.w)));
        vmin = fminf(vmin, fminf(fminf(b.x, b.y), fminf(b.z, b.w)));
        vmax = fmaxf(vmax, fmaxf(fmaxf(b.x, b.y), fmaxf(b.z, b.w)));

        u64 a0 = __ballot(a.x > 0.5f), a1 = __ballot(a.y > 0.5f);
        u64 a2 = __ballot(a.z > 0.5f), a3 = __ballot(a.w > 0.5f);
        u64 b0 = __ballot(b.x > 0.5f), b1 = __ballot(b.y > 0.5f);
        u64 b2 = __ballot(b.z > 0.5f), b3 = __ballot(b.w > 0.5f);

        const int m = lane & 3;
        u64 wa = (m == 0) ? a0 : (m == 1) ? a1 : (m == 2) ? a2 : a3;
        u64 wb = (m == 0) ? b0 : (m == 1) ? b1 : (m == 2) ? b2 : b3;
        if (lane < 8) {
            const int gg = (lane < 4) ? g : g2;
            bits[(size_t)gg * 4 + m] = (lane < 4) ? wa : wb;
        }
    }

    for (int off = 32; off > 0; off >>= 1) {
        vmin = fminf(vmin, __shfl_down(vmin, off));
        vmax = fmaxf(vmax, __shfl_down(vmax, off));
    }
    if (lane == 0) { redMn[wv] = encf(vmin); redMx[wv] = encf(vmax); }
    __syncthreads();
    if (tid == 0) {
        unsigned mn = 0xFFFFFFFFu, mx = 0u;
        #pragma unroll
        for (int i = 0; i < 4; ++i) { mn = min(mn, redMn[i]); mx = max(mx, redMx[i]); }
        atomicMin(&uws[0], mn);
        atomicMax(&uws[1], mx);
    }
}

// ---------------- K2: bit plane -> edge plane (shfl morphology, no LDS) -----
// Wave handles 4 rows x 16 words: lane = (subrow<<4) | w. Vertical OR/AND by
// 5 clamped row loads; horizontal +-2 via shfl within the 16-lane group,
// reproducing the interleaved-domain wrap/funnel logic of the fused kernel.
__global__ __launch_bounds__(256) void bbl_edge(
        const u64* __restrict__ bits, u64* __restrict__ eplane) {
    const int tid  = threadIdx.x;
    const int lane = tid & 63;
    const int wv   = tid >> 6;
    const int waveId = __builtin_amdgcn_readfirstlane(blockIdx.x * 4 + wv);

    const int R  = waveId * 4 + (lane >> 4);   // flat row, one pass covers all
    const int r  = R & (IMG - 1);
    const int rb = R - r;                       // image base row
    const int w  = lane & 15;

    const int lo = max(r - 2, 0), hi = min(r + 2, IMG - 1);
    u64 vd = 0ULL, ve = ~0ULL;
    for (int rr = lo; rr <= hi; ++rr) {
        u64 b = bits[(size_t)(rb + rr) * WORDS + w];
        vd |= b; ve &= b;
    }

    const int k = w & 3;
    u64 hd = vd, he_ = ve;
    #pragma unroll
    for (int dd = 0; dd < 4; ++dd) {
        const int delta = (dd < 2) ? dd - 2 : dd - 1;  // -2,-1,1,2
        const int kp = k + delta;
        u64 td, te;
        if (kp >= 0 && kp <= 3) {               // same 256-block, aligned
            td = __shfl(vd, w + delta, 16);
            te = __shfl(ve, w + delta, 16);
        } else if (kp > 3) {                    // wraps toward next block
            const int wi = w + delta - 4, wn = w + delta;
            u64 vdi = __shfl(vd, wi, 16),      vei = __shfl(ve, wi, 16);
            u64 vdn = __shfl(vd, wn & 15, 16), ven = __shfl(ve, wn & 15, 16);
            u64 nd = (wn <= 15) ? vdn : 0ULL;   // OOB col: dilate id
            u64 ne = (wn <= 15) ? ven : ~0ULL;  // OOB col: erode id
            td = (vdi >> 1) | (nd << 63);
            te = (vei >> 1) | (ne << 63);
        } else {                                // wraps toward prev block
            const int wi = w + delta + 4, wn = w + delta;
            u64 vdi = __shfl(vd, wi, 16),      vei = __shfl(ve, wi, 16);
            u64 vdn = __shfl(vd, wn & 15, 16), ven = __shfl(ve, wn & 15, 16);
            u64 nd = (wn >= 0) ? vdn : 0ULL;
            u64 ne = (wn >= 0) ? ven : ~0ULL;
            td = (vdi << 1) | (nd >> 63);
            te = (vei << 1) | (ne >> 63);
        }
        hd |= td; he_ &= te;
    }
    eplane[(size_t)R * WORDS + w] = hd & ~he_;
}

// ---------------- K3: pred stream + scalar bit-words -> sums (flat) ---------
__global__ __launch_bounds__(256) void bbl_loss(
        const float* __restrict__ pred,
        const u64* __restrict__ bits, const u64* __restrict__ eplane,
        double* __restrict__ dws) {
    __shared__ float redS1[4], redSe[4];
    const int tid  = threadIdx.x;
    const int lane = tid & 63;
    const int wv   = tid >> 6;
    const int waveId = __builtin_amdgcn_readfirstlane(blockIdx.x * 4 + wv);

    float s1 = 0.f, se = 0.f;
    const float4* pp = (const float4*)pred;

    for (int g = waveId; g < NGRP; g += 2 * NWAVES) {   // 8 iterations
        const int g2 = g + NWAVES;
        float4 a = pp[(size_t)g  * 64 + lane];
        float4 b = pp[(size_t)g2 * 64 + lane];
        // wave-uniform word loads (scalar path via readfirstlane'd g)
        u64 ta0 = bits[(size_t)g * 4 + 0],   ta1 = bits[(size_t)g * 4 + 1];
        u64 ta2 = bits[(size_t)g * 4 + 2],   ta3 = bits[(size_t)g * 4 + 3];
        u64 ea0 = eplane[(size_t)g * 4 + 0], ea1 = eplane[(size_t)g * 4 + 1];
        u64 ea2 = eplane[(size_t)g * 4 + 2], ea3 = eplane[(size_t)g * 4 + 3];
        u64 tb0 = bits[(size_t)g2 * 4 + 0],   tb1 = bits[(size_t)g2 * 4 + 1];
        u64 tb2 = bits[(size_t)g2 * 4 + 2],   tb3 = bits[(size_t)g2 * 4 + 3];
        u64 eb0 = eplane[(size_t)g2 * 4 + 0], eb1 = eplane[(size_t)g2 * 4 + 1];
        u64 eb2 = eplane[(size_t)g2 * 4 + 2], eb3 = eplane[(size_t)g2 * 4 + 3];

        float x, l;
        x = a.x; l = fmaxf(x, 0.f) + __logf(1.f + __expf(-fabsf(x)))
                    - (((ta0 >> lane) & 1ULL) ? x : 0.f);
        s1 += l; se += ((ea0 >> lane) & 1ULL) ? l : 0.f;
        x = a.y; l = fmaxf(x, 0.f) + __logf(1.f + __expf(-fabsf(x)))
                    - (((ta1 >> lane) & 1ULL) ? x : 0.f);
        s1 += l; se += ((ea1 >> lane) & 1ULL) ? l : 0.f;
        x = a.z; l = fmaxf(x, 0.f) + __logf(1.f + __expf(-fabsf(x)))
                    - (((ta2 >> lane) & 1ULL) ? x : 0.f);
        s1 += l; se += ((ea2 >> lane) & 1ULL) ? l : 0.f;
        x = a.w; l = fmaxf(x, 0.f) + __logf(1.f + __expf(-fabsf(x)))
                    - (((ta3 >> lane) & 1ULL) ? x : 0.f);
        s1 += l; se += ((ea3 >> lane) & 1ULL) ? l : 0.f;

        x = b.x; l = fmaxf(x, 0.f) + __logf(1.f + __expf(-fabsf(x)))
                    - (((tb0 >> lane) & 1ULL) ? x : 0.f);
        s1 += l; se += ((eb0 >> lane) & 1ULL) ? l : 0.f;
        x = b.y; l = fmaxf(x, 0.f) + __logf(1.f + __expf(-fabsf(x)))
                    - (((tb1 >> lane) & 1ULL) ? x : 0.f);
        s1 += l; se += ((eb1 >> lane) & 1ULL) ? l : 0.f;
        x = b.z; l = fmaxf(x, 0.f) + __logf(1.f + __expf(-fabsf(x)))
                    - (((tb2 >> lane) & 1ULL) ? x : 0.f);
        s1 += l; se += ((eb2 >> lane) & 1ULL) ? l : 0.f;
        x = b.w; l = fmaxf(x, 0.f) + __logf(1.f + __expf(-fabsf(x)))
                    - (((tb3 >> lane) & 1ULL) ? x : 0.f);
        s1 += l; se += ((eb3 >> lane) & 1ULL) ? l : 0.f;
    }

    for (int off = 32; off > 0; off >>= 1) {
        s1 += __shfl_down(s1, off);
        se += __shfl_down(se, off);
    }
    if (lane == 0) { redS1[wv] = s1; redSe[wv] = se; }
    __syncthreads();
    if (tid == 0) {
        float S1 = 0.f, Se = 0.f;
        #pragma unroll
        for (int i = 0; i < 4; ++i) { S1 += redS1[i]; Se += redSe[i]; }
        atomicAdd(&dws[0], (double)S1);
        atomicAdd(&dws[1], (double)Se);
    }
}

// ---------------- fallback: R0 fused kernel (used if ws too small) ----------
__global__ __launch_bounds__(512) void bbl_main(
        const float* __restrict__ pred,
        const float* __restrict__ target,
        double* __restrict__ dws, unsigned* __restrict__ uws) {
    __shared__ u64 Bm[MAXROWS][WORDS];
    __shared__ u64 Vd[BAND][WORDS];
    __shared__ u64 Ve[BAND][WORDS];
    __shared__ u64 Em[BAND][WORDS];
    __shared__ float    redS1[8], redSe[8];
    __shared__ unsigned redMn[8], redMx[8];

    const int tid  = threadIdx.x;
    const int lane = tid & 63;
    const int wid  = tid >> 6;
    const int img  = blockIdx.x / NBANDS;
    const int r0   = (blockIdx.x % NBANDS) * BAND;
    const int hs   = max(r0 - HALO, 0);
    const int he   = min(r0 + BAND + HALO, IMG);
    const int nLoaded = he - hs;
    const size_t base = (size_t)img * IMG * IMG;

    float vmin = 3.4e38f, vmax = -3.4e38f;

    for (int lr = wid; lr < nLoaded; lr += 8) {
        const float4* rowp = (const float4*)(target + base + (size_t)(hs + lr) * IMG);
        #pragma unroll
        for (int it = 0; it < 4; ++it) {
            float4 v = rowp[it * 64 + lane];
            vmin = fminf(vmin, fminf(fminf(v.x, v.y), fminf(v.z, v.w)));
            vmax = fmaxf(vmax, fmaxf(fmaxf(v.x, v.y), fmaxf(v.z, v.w)));
            u64 b0 = __ballot(v.x > 0.5f);
            u64 b1 = __ballot(v.y > 0.5f);
            u64 b2 = __ballot(v.z > 0.5f);
            u64 b3 = __ballot(v.w > 0.5f);
            if (lane < 4) {
                u64 w = (lane == 0) ? b0 : (lane == 1) ? b1 : (lane == 2) ? b2 : b3;
                Bm[lr][it * 4 + lane] = w;
            }
        }
    }
    __syncthreads();
    {
        const int orow = tid >> 4, w = tid & 15;
        const int gr = r0 + orow;
        const int lo = max(gr - 2, 0), hi = min(gr + 2, IMG - 1);
        u64 vd = 0ULL, ve = ~0ULL;
        for (int g = lo; g <= hi; ++g) { u64 b = Bm[g - hs][w]; vd |= b; ve &= b; }
        Vd[orow][w] = vd; Ve[orow][w] = ve;
    }
    __syncthreads();
    {
        const int orow = tid >> 4, w = tid & 15;
        const int k = w & 3;
        u64 hd = Vd[orow][w], he_ = Ve[orow][w];
        #pragma unroll
        for (int dd = 0; dd < 4; ++dd) {
            const int delta = (dd < 2) ? dd - 2 : dd - 1;
            const int kp = k + delta;
            u64 td, te;
            if (kp >= 0 && kp <= 3) {
                td = Vd[orow][w + delta];
                te = Ve[orow][w + delta];
            } else if (kp > 3) {
                const int wi = w + delta - 4, wn = w + delta;
                u64 nd = (wn <= 15) ? Vd[orow][wn] : 0ULL;
                u64 ne = (wn <= 15) ? Ve[orow][wn] : ~0ULL;
                td = (Vd[orow][wi] >> 1) | (nd << 63);
                te = (Ve[orow][wi] >> 1) | (ne << 63);
            } else {
                const int wi = w + delta + 4, wn = w + delta;
                u64 nd = (wn >= 0) ? Vd[orow][wn] : 0ULL;
                u64 ne = (wn >= 0) ? Ve[orow][wn] : ~0ULL;
                td = (Vd[orow][wi] << 1) | (nd >> 63);
                te = (Ve[orow][wi] << 1) | (ne >> 63);
            }
            hd |= td; he_ &= te;
        }
        Em[orow][w] = hd & ~he_;
    }
    __syncthreads();

    float s1 = 0.f, se = 0.f;
    for (int orow = wid * 4; orow < wid * 4 + 4; ++orow) {
        const int gr = r0 + orow, lr = gr - hs;
        const float4* rowp = (const float4*)(pred + base + (size_t)gr * IMG);
        #pragma unroll
        for (int it = 0; it < 4; ++it) {
            float4 p = rowp[it * 64 + lane];
            u64 e0 = Em[orow][it * 4 + 0], e1 = Em[orow][it * 4 + 1];
            u64 e2 = Em[orow][it * 4 + 2], e3 = Em[orow][it * 4 + 3];
            u64 t0 = Bm[lr][it * 4 + 0],   t1 = Bm[lr][it * 4 + 1];
            u64 t2 = Bm[lr][it * 4 + 2],   t3 = Bm[lr][it * 4 + 3];
            float x, t, loss;
            x = p.x; t = (float)((unsigned)((t0 >> lane) & 1ULL));
            loss = fmaxf(x, 0.f) - x * t + __logf(1.f + __expf(-fabsf(x)));
            s1 += loss; se += ((e0 >> lane) & 1ULL) ? loss : 0.f;
            x = p.y; t = (float)((unsigned)((t1 >> lane) & 1ULL));
            loss = fmaxf(x, 0.f) - x * t + __logf(1.f + __expf(-fabsf(x)));
            s1 += loss; se += ((e1 >> lane) & 1ULL) ? loss : 0.f;
            x = p.z; t = (float)((unsigned)((t2 >> lane) & 1ULL));
            loss = fmaxf(x, 0.f) - x * t + __logf(1.f + __expf(-fabsf(x)));
            s1 += loss; se += ((e2 >> lane) & 1ULL) ? loss : 0.f;
            x = p.w; t = (float)((unsigned)((t3 >> lane) & 1ULL));
            loss = fmaxf(x, 0.f) - x * t + __logf(1.f + __expf(-fabsf(x)));
            s1 += loss; se += ((e3 >> lane) & 1ULL) ? loss : 0.f;
        }
    }

    for (int off = 32; off > 0; off >>= 1) {
        s1   += __shfl_down(s1, off);
        se   += __shfl_down(se, off);
        vmin  = fminf(vmin, __shfl_down(vmin, off));
        vmax  = fmaxf(vmax, __shfl_down(vmax, off));
    }
    if (lane == 0) {
        redS1[wid] = s1; redSe[wid] = se;
        redMn[wid] = encf(vmin); redMx[wid] = encf(vmax);
    }
    __syncthreads();
    if (tid == 0) {
        float S1 = 0.f, Se = 0.f; unsigned mn = 0xFFFFFFFFu, mx = 0u;
        #pragma unroll
        for (int i = 0; i < 8; ++i) {
            S1 += redS1[i]; Se += redSe[i];
            mn = min(mn, redMn[i]); mx = max(mx, redMx[i]);
        }
        atomicAdd(&dws[0], (double)S1);
        atomicAdd(&dws[1], (double)Se);
        atomicMin(&uws[0], mn);
        atomicMax(&uws[1], mx);
    }
}

__global__ void bbl_fin(const double* __restrict__ dws,
                        const unsigned* __restrict__ uws,
                        float* __restrict__ out) {
    if (threadIdx.x == 0) {
        float fmin = decf(uws[0]);
        float fmax = decf(uws[1]);
        bool cond = (fmax == 1.0f) && (fmin == 0.0f);
        double s = cond ? (dws[0] - 0.9 * dws[1]) : dws[0];
        out[0] = (float)(s / NTOT);
    }
}

extern "C" void kernel_launch(void* const* d_in, const int* in_sizes, int n_in,
                              void* d_out, int out_size, void* d_ws, size_t ws_size,
                              hipStream_t stream) {
    const float* pred   = (const float*)d_in[0];
    const float* target = (const float*)d_in[1];
    double*   dws = (double*)d_ws;
    unsigned* uws = (unsigned*)(dws + 2);
    float*    out = (float*)d_out;

    const size_t bits_off  = 64;
    const size_t plane_sz  = (size_t)NROWS * WORDS * sizeof(u64);   // 4 MB
    const size_t need      = bits_off + 2 * plane_sz;               // 8 MB + 64

    hipLaunchKernelGGL(bbl_init, dim3(1), dim3(64), 0, stream, dws, uws);
    if (ws_size >= need) {
        u64* bits   = (u64*)((char*)d_ws + bits_off);
        u64* eplane = bits + (size_t)NROWS * WORDS;
        hipLaunchKernelGGL(bbl_bits, dim3(2048), dim3(256), 0, stream,
                           target, bits, uws);
        hipLaunchKernelGGL(bbl_edge, dim3(2048), dim3(256), 0, stream,
                           bits, eplane);
        hipLaunchKernelGGL(bbl_loss, dim3(2048), dim3(256), 0, stream,
                           pred, bits, eplane, dws);
    } else {
        hipLaunchKernelGGL(bbl_main, dim3(NIMG * NBANDS), dim3(512), 0, stream,
                           pred, target, dws, uws);
    }
    hipLaunchKernelGGL(bbl_fin, dim3(1), dim3(64), 0, stream, dws, uws, out);
}

// Round 8
// 331.836 us; speedup vs baseline: 1.0741x; 1.0741x over previous
//
#include <hip/hip_runtime.h>

// pred, target: [32,1,1024,1024] f32 -> scalar f32 = mean((softplus(p)-p*t)*w),
// w = 0.1 on 5x5 morphological gradient of binarized target, gated on
// cond = (t.max()==1 && t.min()==0).
//
// R8: champion fused structure (R0: 119us, absmax 0.0; all splits/flat chains
// regressed) + three concurrency levers:
//   - BAND 16, 256-thr blocks, 2048 blocks = 8 blocks/CU capacity (was 4):
//     cross-block overlap of the barrier-phased sections.
//   - 4 nontemporal float4 loads hoisted per row in both stream phases:
//     3 loads outstanding while consuming the 1st; nt = no L1/L2 allocate
//     for once-read streams (268MB through 4MB/XCD L2 otherwise churns).
//   - no min-waves launch_bounds clause (R6's (512,8) crushed VGPR to 28 and
//     regressed to 133us).
// Summation order per block unchanged in spirit from R0 (identical loss
// expression; per-wave f32 accum -> LDS -> double atomics).

#define IMG     1024
#define BAND    16
#define NBANDS  (IMG / BAND)     // 64
#define NIMG    32
#define WORDS   16               // 1024 cols / 64 bits
#define HALO    2
#define MAXROWS (BAND + 2 * HALO)  // 20
#define NTOT    33554432.0

typedef unsigned long long u64;
typedef float v4f __attribute__((ext_vector_type(4)));

__device__ __forceinline__ v4f ntl4(const float* p) {
    return __builtin_nontemporal_load((const v4f*)p);
}

__device__ __forceinline__ unsigned encf(float f) {
    unsigned u = __float_as_uint(f);
    return (u & 0x80000000u) ? ~u : (u | 0x80000000u);
}
__device__ __forceinline__ float decf(unsigned e) {
    unsigned u = (e & 0x80000000u) ? (e & 0x7fffffffu) : ~e;
    return __uint_as_float(u);
}

__global__ void bbl_init(double* dws, unsigned* uws) {
    if (threadIdx.x == 0) {
        dws[0] = 0.0; dws[1] = 0.0;
        uws[0] = 0xFFFFFFFFu;   // running min (encoded)
        uws[1] = 0u;            // running max (encoded)
    }
}

__global__ __launch_bounds__(256) void bbl_main(
        const float* __restrict__ pred,
        const float* __restrict__ target,
        double* __restrict__ dws, unsigned* __restrict__ uws) {
    __shared__ u64 Bm[MAXROWS][WORDS];   // raw bits (t>0.5), interleaved layout
    __shared__ u64 Vd[BAND][WORDS];      // vertical OR  (dilate, 5 rows)
    __shared__ u64 Ve[BAND][WORDS];      // vertical AND (erode, 5 rows)
    __shared__ u64 Em[BAND][WORDS];      // edge bits
    __shared__ float    redS1[4], redSe[4];
    __shared__ unsigned redMn[4], redMx[4];

    const int tid  = threadIdx.x;
    const int lane = tid & 63;
    const int wid  = tid >> 6;           // 4 waves
    const int img  = blockIdx.x / NBANDS;
    const int r0   = (blockIdx.x % NBANDS) * BAND;
    const int hs   = max(r0 - HALO, 0);
    const int he   = min(r0 + BAND + HALO, IMG);
    const int nLoaded = he - hs;
    const size_t base = (size_t)img * IMG * IMG;
    const float* tb = target + base;

    float vmin = 3.4e38f, vmax = -3.4e38f;

    // ---- 1a: stream target rows (band+halo); 4 nt loads hoisted per row;
    //          ballot -> mask words (word it*4+m holds cols 256*it+4*lane+m
    //          at bit lane)
    for (int lr = wid; lr < nLoaded; lr += 4) {
        const float* rp = tb + (size_t)(hs + lr) * IMG + 4 * lane;
        v4f q0 = ntl4(rp);
        v4f q1 = ntl4(rp + 256);
        v4f q2 = ntl4(rp + 512);
        v4f q3 = ntl4(rp + 768);
        #pragma unroll
        for (int it = 0; it < 4; ++it) {
            v4f v = (it == 0) ? q0 : (it == 1) ? q1 : (it == 2) ? q2 : q3;
            vmin = fminf(vmin, fminf(fminf(v.x, v.y), fminf(v.z, v.w)));
            vmax = fmaxf(vmax, fmaxf(fmaxf(v.x, v.y), fmaxf(v.z, v.w)));
            u64 b0 = __ballot(v.x > 0.5f);
            u64 b1 = __ballot(v.y > 0.5f);
            u64 b2 = __ballot(v.z > 0.5f);
            u64 b3 = __ballot(v.w > 0.5f);
            if (lane < 4) {
                u64 w = (lane == 0) ? b0 : (lane == 1) ? b1 : (lane == 2) ? b2 : b3;
                Bm[lr][it * 4 + lane] = w;
            }
        }
    }
    __syncthreads();

    // ---- 1b: vertical OR/AND over rows gr-2..gr+2 (clamped; skipped rows are
    //          identity, matching -inf/+inf reduce_window padding)
    {
        const int orow = tid >> 4, w = tid & 15;      // 16*16 = 256 = blockDim
        const int gr = r0 + orow;
        const int lo = max(gr - 2, 0), hi = min(gr + 2, IMG - 1);
        u64 vd = 0ULL, ve = ~0ULL;
        for (int g = lo; g <= hi; ++g) { u64 b = Bm[g - hs][w]; vd |= b; ve &= b; }
        Vd[orow][w] = vd; Ve[orow][w] = ve;
    }
    __syncthreads();

    // ---- 1c: horizontal +-2 in interleaved domain; edge = dilate & ~erode
    {
        const int orow = tid >> 4, w = tid & 15;
        const int k = w & 3;
        u64 hd = Vd[orow][w], he_ = Ve[orow][w];
        #pragma unroll
        for (int dd = 0; dd < 4; ++dd) {
            const int delta = (dd < 2) ? dd - 2 : dd - 1;  // -2,-1,1,2
            const int kp = k + delta;
            u64 td, te;
            if (kp >= 0 && kp <= 3) {               // same 256-block, aligned
                td = Vd[orow][w + delta];
                te = Ve[orow][w + delta];
            } else if (kp > 3) {                    // wraps toward next block
                const int wi = w + delta - 4, wn = w + delta;
                u64 nd = (wn <= 15) ? Vd[orow][wn] : 0ULL;   // OOB col: dilate id
                u64 ne = (wn <= 15) ? Ve[orow][wn] : ~0ULL;  // OOB col: erode id
                td = (Vd[orow][wi] >> 1) | (nd << 63);
                te = (Ve[orow][wi] >> 1) | (ne << 63);
            } else {                                // wraps toward prev block
                const int wi = w + delta + 4, wn = w + delta;
                u64 nd = (wn >= 0) ? Vd[orow][wn] : 0ULL;
                u64 ne = (wn >= 0) ? Ve[orow][wn] : ~0ULL;
                td = (Vd[orow][wi] << 1) | (nd >> 63);
                te = (Ve[orow][wi] << 1) | (ne >> 63);
            }
            hd |= td; he_ &= te;
        }
        Em[orow][w] = hd & ~he_;
    }
    __syncthreads();

    // ---- 2: stream pred; 4 nt loads hoisted per row; bits via LDS broadcast
    float s1 = 0.f, se = 0.f;
    for (int orow = wid * 4; orow < wid * 4 + 4; ++orow) {   // 4 waves x 4 rows
        const int gr = r0 + orow, lr = gr - hs;
        const float* rp = pred + base + (size_t)gr * IMG + 4 * lane;
        v4f p0 = ntl4(rp);
        v4f p1 = ntl4(rp + 256);
        v4f p2 = ntl4(rp + 512);
        v4f p3 = ntl4(rp + 768);
        #pragma unroll
        for (int it = 0; it < 4; ++it) {
            v4f p = (it == 0) ? p0 : (it == 1) ? p1 : (it == 2) ? p2 : p3;
            u64 e0 = Em[orow][it * 4 + 0], e1 = Em[orow][it * 4 + 1];
            u64 e2 = Em[orow][it * 4 + 2], e3 = Em[orow][it * 4 + 3];
            u64 t0 = Bm[lr][it * 4 + 0],   t1 = Bm[lr][it * 4 + 1];
            u64 t2 = Bm[lr][it * 4 + 2],   t3 = Bm[lr][it * 4 + 3];
            float x, t, loss;
            x = p.x; t = (float)((unsigned)((t0 >> lane) & 1ULL));
            loss = fmaxf(x, 0.f) - x * t + __logf(1.f + __expf(-fabsf(x)));
            s1 += loss; se += ((e0 >> lane) & 1ULL) ? loss : 0.f;
            x = p.y; t = (float)((unsigned)((t1 >> lane) & 1ULL));
            loss = fmaxf(x, 0.f) - x * t + __logf(1.f + __expf(-fabsf(x)));
            s1 += loss; se += ((e1 >> lane) & 1ULL) ? loss : 0.f;
            x = p.z; t = (float)((unsigned)((t2 >> lane) & 1ULL));
            loss = fmaxf(x, 0.f) - x * t + __logf(1.f + __expf(-fabsf(x)));
            s1 += loss; se += ((e2 >> lane) & 1ULL) ? loss : 0.f;
            x = p.w; t = (float)((unsigned)((t3 >> lane) & 1ULL));
            loss = fmaxf(x, 0.f) - x * t + __logf(1.f + __expf(-fabsf(x)));
            s1 += loss; se += ((e3 >> lane) & 1ULL) ? loss : 0.f;
        }
    }

    // ---- reduce: wave shuffles, 4 waves via LDS, one atomic set per block
    for (int off = 32; off > 0; off >>= 1) {
        s1   += __shfl_down(s1, off);
        se   += __shfl_down(se, off);
        vmin  = fminf(vmin, __shfl_down(vmin, off));
        vmax  = fmaxf(vmax, __shfl_down(vmax, off));
    }
    if (lane == 0) {
        redS1[wid] = s1; redSe[wid] = se;
        redMn[wid] = encf(vmin); redMx[wid] = encf(vmax);
    }
    __syncthreads();
    if (tid == 0) {
        float S1 = 0.f, Se = 0.f; unsigned mn = 0xFFFFFFFFu, mx = 0u;
        #pragma unroll
        for (int i = 0; i < 4; ++i) {
            S1 += redS1[i]; Se += redSe[i];
            mn = min(mn, redMn[i]); mx = max(mx, redMx[i]);
        }
        atomicAdd(&dws[0], (double)S1);
        atomicAdd(&dws[1], (double)Se);
        atomicMin(&uws[0], mn);
        atomicMax(&uws[1], mx);
    }
}

__global__ void bbl_fin(const double* __restrict__ dws,
                        const unsigned* __restrict__ uws,
                        float* __restrict__ out) {
    if (threadIdx.x == 0) {
        float fmin = decf(uws[0]);
        float fmax = decf(uws[1]);
        bool cond = (fmax == 1.0f) && (fmin == 0.0f);
        double s = cond ? (dws[0] - 0.9 * dws[1]) : dws[0];
        out[0] = (float)(s / NTOT);
    }
}

extern "C" void kernel_launch(void* const* d_in, const int* in_sizes, int n_in,
                              void* d_out, int out_size, void* d_ws, size_t ws_size,
                              hipStream_t stream) {
    const float* pred   = (const float*)d_in[0];
    const float* target = (const float*)d_in[1];
    double*   dws = (double*)d_ws;
    unsigned* uws = (unsigned*)(dws + 2);
    float*    out = (float*)d_out;

    hipLaunchKernelGGL(bbl_init, dim3(1), dim3(64), 0, stream, dws, uws);
    hipLaunchKernelGGL(bbl_main, dim3(NIMG * NBANDS), dim3(256), 0, stream,
                       pred, target, dws, uws);
    hipLaunchKernelGGL(bbl_fin, dim3(1), dim3(64), 0, stream, dws, uws, out);
}